// Round 6
// baseline (451.699 us; speedup 1.0000x reference)
//
#include <hip/hip_runtime.h>
#include <cstdio>
#include <cstdint>

// Problem constants
#define B_    16
#define N_    577
#define C_    768
#define H_    12
#define D_    64
#define KKEEP 288            // max(1, int(576*0.5))
#define SCALE 0.125f         // 64^-0.5 (exact power of 2)
#define M_TOT (B_ * N_)      // 9232
#define VTS   640            // vt row stride (>= 10*64, 16B-aligned)
#define NKT   24             // K tiles (768/32)

typedef __bf16 bf16x8_t __attribute__((ext_vector_type(8)));
typedef float  f32x4_t  __attribute__((ext_vector_type(4)));
typedef unsigned int u32x4_t __attribute__((ext_vector_type(4)));

__device__ __forceinline__ f32x4_t mfma_bf16(bf16x8_t a, bf16x8_t b, f32x4_t c) {
    return __builtin_amdgcn_mfma_f32_16x16x32_bf16(a, b, c, 0, 0, 0);
}

// async global->LDS, 16B per lane (lds dest = wave-uniform base + lane*16)
__device__ __forceinline__ void gload16(const ushort* g, ushort* l) {
    __builtin_amdgcn_global_load_lds(
        (const __attribute__((address_space(1))) void*)g,
        (__attribute__((address_space(3))) void*)l, 16, 0, 0);
}

// RTZ split of f32 into two bf16 bit patterns (x ~= hi + lo, err ~2^-16 |x|)
__device__ __forceinline__ void splitf(float x, unsigned int &hi, unsigned int &lo) {
    unsigned int u = __float_as_uint(x);
    hi = u >> 16;
    float r = x - __uint_as_float(u & 0xffff0000u);
    lo = __float_as_uint(r) >> 16;
}
__device__ __forceinline__ unsigned int bf16rne(float x) {
    unsigned int u = __float_as_uint(x);
    return (u + 0x7fffu + ((u >> 16) & 1u)) >> 16;
}
// packed-split pair merges: p = hi|lo<<16 per element
__device__ __forceinline__ unsigned hp(unsigned a, unsigned b) { return (a & 0xffffu) | (b << 16); }
__device__ __forceinline__ unsigned lp(unsigned a, unsigned b) { return (a >> 16) | (b & 0xffff0000u); }

__device__ __forceinline__ void unpack16(const unsigned* p, u32x4_t &hc0, u32x4_t &hc1,
                                         u32x4_t &lc0, u32x4_t &lc1) {
    hc0 = (u32x4_t){hp(p[0], p[1]), hp(p[2], p[3]), hp(p[4], p[5]), hp(p[6], p[7])};
    hc1 = (u32x4_t){hp(p[8], p[9]), hp(p[10], p[11]), hp(p[12], p[13]), hp(p[14], p[15])};
    lc0 = (u32x4_t){lp(p[0], p[1]), lp(p[2], p[3]), lp(p[4], p[5]), lp(p[6], p[7])};
    lc1 = (u32x4_t){lp(p[8], p[9]), lp(p[10], p[11]), lp(p[12], p[13]), lp(p[14], p[15])};
}

// ---------------------------------------------------------------------------
// Prepass: pack f32 [nrows x 768] into split hi/lo bf16 planes in TILED,
// PRE-SWIZZLED layout: tile (mt,kt) = 4096 ushorts at (mt*NKT+kt)*4096;
// within tile, LDS-linear offset row*32 + p*8 + e holds source column
// (p ^ ((row>>1)&3))*8 + e  (matches fragT's read swizzle).
// One block per tile, 256 threads; thread w -> row w/2, phys slots 2h,2h+1.
// ---------------------------------------------------------------------------
__global__ __launch_bounds__(256) void pack_tiles_kernel(const float* __restrict__ src,
                                                         ushort* __restrict__ dH,
                                                         ushort* __restrict__ dL,
                                                         int nrows) {
    int tile = blockIdx.x;
    int kt = tile % NKT, mt = tile / NKT;
    int w = threadIdx.x;
    int row = w >> 1, h = w & 1;
    int m = mt * 128 + row;
    int sw = (row >> 1) & 3;
    float f[16];
    if (m < nrows) {
        const float* s = src + (size_t)m * C_ + kt * 32;
        int sa = (2 * h) ^ sw, sb = (2 * h + 1) ^ sw;   // logical slots
        *(float4*)&f[0]  = *(const float4*)(s + sa * 8);
        *(float4*)&f[4]  = *(const float4*)(s + sa * 8 + 4);
        *(float4*)&f[8]  = *(const float4*)(s + sb * 8);
        *(float4*)&f[12] = *(const float4*)(s + sb * 8 + 4);
    } else {
#pragma unroll
        for (int i = 0; i < 16; i++) f[i] = 0.f;
    }
    unsigned hi[16], lo[16];
#pragma unroll
    for (int i = 0; i < 16; i++) splitf(f[i], hi[i], lo[i]);
    u32x4_t h0 = {hi[0] | (hi[1] << 16), hi[2] | (hi[3] << 16),
                  hi[4] | (hi[5] << 16), hi[6] | (hi[7] << 16)};
    u32x4_t h1 = {hi[8] | (hi[9] << 16), hi[10] | (hi[11] << 16),
                  hi[12] | (hi[13] << 16), hi[14] | (hi[15] << 16)};
    u32x4_t l0 = {lo[0] | (lo[1] << 16), lo[2] | (lo[3] << 16),
                  lo[4] | (lo[5] << 16), lo[6] | (lo[7] << 16)};
    u32x4_t l1 = {lo[8] | (lo[9] << 16), lo[10] | (lo[11] << 16),
                  lo[12] | (lo[13] << 16), lo[14] | (lo[15] << 16)};
    size_t dbase = (size_t)tile * 4096 + row * 32;
    *(u32x4_t*)&dH[dbase + (2 * h) * 8]     = h0;
    *(u32x4_t*)&dH[dbase + (2 * h + 1) * 8] = h1;
    *(u32x4_t*)&dL[dbase + (2 * h) * 8]     = l0;
    *(u32x4_t*)&dL[dbase + (2 * h + 1) * 8] = l1;
}

// Prepass: f32 -> bf16 RNE, 8 elems/thread
__global__ __launch_bounds__(256) void pack_rne_kernel(const float* __restrict__ src,
                                                       ushort* __restrict__ dst, int n8) {
    int i = blockIdx.x * 256 + threadIdx.x;
    if (i >= n8) return;
    float4 f0 = ((const float4*)src)[2 * i];
    float4 f1 = ((const float4*)src)[2 * i + 1];
    u32x4_t o = {bf16rne(f0.x) | (bf16rne(f0.y) << 16),
                 bf16rne(f0.z) | (bf16rne(f0.w) << 16),
                 bf16rne(f1.x) | (bf16rne(f1.y) << 16),
                 bf16rne(f1.z) | (bf16rne(f1.w) << 16)};
    *(u32x4_t*)&dst[(size_t)i * 8] = o;
}

// ===========================================================================
// 64x64 bf16 LDS tiles: 64 ushort/row, 8 slots of 8; phys slot = logical^(row&7)
// ===========================================================================
__device__ __forceinline__ bf16x8_t fragT(const ushort* H, int row, int c, int ls) {
    int phys = ((c << 2) + ls) ^ (row & 7);
    return __builtin_bit_cast(bf16x8_t, *(const u32x4_t*)&H[(row << 6) + (phys << 3)]);
}

// stage 64x64 packed-split tile (rows row0.. from [N][64] u32) into Hh/Hl LDS
__device__ __forceinline__ void stage_packed64(const unsigned* __restrict__ base, int row0,
                                               ushort* Hh, ushort* Hl, int tid) {
    int r = tid >> 2, qd = tid & 3;
    int rn = row0 + r;
    unsigned p[16];
    if (rn < N_) {
        const unsigned* src = base + (size_t)rn * D_ + qd * 16;
        *(u32x4_t*)&p[0]  = *(const u32x4_t*)(src);
        *(u32x4_t*)&p[4]  = *(const u32x4_t*)(src + 4);
        *(u32x4_t*)&p[8]  = *(const u32x4_t*)(src + 8);
        *(u32x4_t*)&p[12] = *(const u32x4_t*)(src + 12);
    } else {
#pragma unroll
        for (int i = 0; i < 16; i++) p[i] = 0;
    }
    u32x4_t hc0, hc1, lc0, lc1;
    unpack16(p, hc0, hc1, lc0, lc1);
    int s0 = (2 * qd) ^ (r & 7), s1 = (2 * qd + 1) ^ (r & 7);
    *(u32x4_t*)&Hh[(r << 6) + (s0 << 3)] = hc0;
    *(u32x4_t*)&Hh[(r << 6) + (s1 << 3)] = hc1;
    *(u32x4_t*)&Hl[(r << 6) + (s0 << 3)] = lc0;
    *(u32x4_t*)&Hl[(r << 6) + (s1 << 3)] = lc1;
}

// stage 64x64 bf16 tile from vt (rows = d, row stride VTS), cols j0..j0+63
__device__ __forceinline__ void stage_vt(const ushort* __restrict__ vtb, int j0,
                                         ushort* Vt, int tid) {
    int r = tid >> 2, qd = tid & 3;
    const ushort* src = vtb + (size_t)r * VTS + j0 + qd * 16;
    u32x4_t c0 = *(const u32x4_t*)(src);
    u32x4_t c1 = *(const u32x4_t*)(src + 8);
    int s0 = (2 * qd) ^ (r & 7), s1 = (2 * qd + 1) ^ (r & 7);
    *(u32x4_t*)&Vt[(r << 6) + (s0 << 3)] = c0;
    *(u32x4_t*)&Vt[(r << 6) + (s1 << 3)] = c1;
}

// ---------------------------------------------------------------------------
// MFMA GEMM 1 (split precision, async-staged planes): qkv = x @ Wqkv^T
// outputs: qpk/kpk packed-split u32 [B,H,N,D] (q pre-scaled), v -> vt bf16^T
// V-columns (n0 >= 2C): 2-term split (drop X*Wlo), skip Bl staging.
// ---------------------------------------------------------------------------
__global__ __launch_bounds__(256) void gemm_qkv_mfma(const ushort* __restrict__ XplH,
                                                     const ushort* __restrict__ XplL,
                                                     const ushort* __restrict__ WplH,
                                                     const ushort* __restrict__ WplL,
                                                     unsigned* __restrict__ qpk,
                                                     unsigned* __restrict__ kpk,
                                                     ushort* __restrict__ vt) {
    __shared__ ushort Ah[4096], Al[4096], Bh[4096], Bl[4096];
    const int tid = threadIdx.x;
    const int lane = tid & 63, wave = tid >> 6;
    const int wr = wave >> 1, wc = wave & 1;
    const int lr = lane & 15, ls = lane >> 4;
    const int m0 = blockIdx.y * 128, n0 = blockIdx.x * 128;
    const int s = n0 / C_;          // 0=q, 1=k, 2=v (block-uniform)
    const bool isv = (s == 2);
    const int o0 = wave * 1024, o1 = o0 + 512;   // ushort offsets, 2KB/wave
    const int la = lane * 8;                     // lane's 16B within the 1KB chunk
    const size_t abase = (size_t)blockIdx.y * NKT * 4096;
    const size_t bbase = (size_t)blockIdx.x * NKT * 4096;
    f32x4_t acc[4][4] = {};
#pragma unroll 1
    for (int kt = 0; kt < NKT; ++kt) {
        const size_t ta = abase + (size_t)kt * 4096;
        const size_t tb = bbase + (size_t)kt * 4096;
        __syncthreads();
        gload16(XplH + ta + o0 + la, &Ah[o0]);
        gload16(XplH + ta + o1 + la, &Ah[o1]);
        gload16(XplL + ta + o0 + la, &Al[o0]);
        gload16(XplL + ta + o1 + la, &Al[o1]);
        gload16(WplH + tb + o0 + la, &Bh[o0]);
        gload16(WplH + tb + o1 + la, &Bh[o1]);
        if (!isv) {
            gload16(WplL + tb + o0 + la, &Bl[o0]);
            gload16(WplL + tb + o1 + la, &Bl[o1]);
        }
        __syncthreads();
        bf16x8_t fah[4], fal[4], fbh[4], fbl[4];
#pragma unroll
        for (int i = 0; i < 4; i++) {
            int rowA = wr * 64 + i * 16 + lr;
            int pa = ls ^ ((rowA >> 1) & 3);
            fah[i] = __builtin_bit_cast(bf16x8_t, *(const u32x4_t*)&Ah[rowA * 32 + pa * 8]);
            fal[i] = __builtin_bit_cast(bf16x8_t, *(const u32x4_t*)&Al[rowA * 32 + pa * 8]);
            int rowB = wc * 64 + i * 16 + lr;
            int pb = ls ^ ((rowB >> 1) & 3);
            fbh[i] = __builtin_bit_cast(bf16x8_t, *(const u32x4_t*)&Bh[rowB * 32 + pb * 8]);
            if (!isv)
                fbl[i] = __builtin_bit_cast(bf16x8_t, *(const u32x4_t*)&Bl[rowB * 32 + pb * 8]);
        }
        if (isv) {
#pragma unroll
            for (int i = 0; i < 4; i++)
#pragma unroll
                for (int j = 0; j < 4; j++) {
                    acc[i][j] = mfma_bf16(fah[i], fbh[j], acc[i][j]);
                    acc[i][j] = mfma_bf16(fal[i], fbh[j], acc[i][j]);
                }
        } else {
#pragma unroll
            for (int i = 0; i < 4; i++)
#pragma unroll
                for (int j = 0; j < 4; j++) {
                    acc[i][j] = mfma_bf16(fah[i], fbh[j], acc[i][j]);
                    acc[i][j] = mfma_bf16(fah[i], fbl[j], acc[i][j]);
                    acc[i][j] = mfma_bf16(fal[i], fbh[j], acc[i][j]);
                }
        }
    }
#pragma unroll
    for (int j = 0; j < 4; j++) {
        int ng = n0 + wc * 64 + j * 16 + lr;
        int hh = (ng % C_) / D_;
        int d = ng % D_;
#pragma unroll
        for (int i = 0; i < 4; i++) {
            int mg0 = m0 + wr * 64 + i * 16 + ls * 4;
#pragma unroll
            for (int r = 0; r < 4; r++) {
                int m = mg0 + r;
                if (m < M_TOT) {
                    int b = m / N_, n = m % N_;
                    if (isv) {
                        vt[((size_t)(b * H_ + hh) * D_ + d) * VTS + n] =
                            (ushort)bf16rne(acc[i][j][r]);
                    } else {
                        float val = acc[i][j][r];
                        if (s == 0) val *= SCALE;
                        unsigned hi, lo;
                        splitf(val, hi, lo);
                        unsigned* dst = (s == 1) ? kpk : qpk;
                        dst[((size_t)(b * H_ + hh) * N_ + n) * D_ + d] = hi | (lo << 16);
                    }
                }
            }
        }
    }
}

// ---------------------------------------------------------------------------
// Pass R: w[bh][q] = 1 / sum_j exp(s)   (swapped S^T MFMA, split, q prescaled)
// ---------------------------------------------------------------------------
__global__ __launch_bounds__(256) void attn_rowsum_mfma(const unsigned* __restrict__ qpk,
                                                        const unsigned* __restrict__ kpk,
                                                        float* __restrict__ w) {
    __shared__ ushort Qh[4096], Ql[4096], Kh[4096], Kl[4096];
    __shared__ float red[4][64];
    int bh = blockIdx.y, q0 = blockIdx.x * 64;
    int tid = threadIdx.x, lane = tid & 63, wv = tid >> 6;
    int lr = lane & 15, ls = lane >> 4;
    const unsigned* qb = qpk + (size_t)bh * N_ * D_;
    const unsigned* kb = kpk + (size_t)bh * N_ * D_;
    stage_packed64(qb, q0, Qh, Ql, tid);
    __syncthreads();
    bf16x8_t fqh[4][2], fql[4][2];   // B operand: n = q = i*16+lr
#pragma unroll
    for (int i = 0; i < 4; i++)
#pragma unroll
        for (int c = 0; c < 2; c++) {
            fqh[i][c] = fragT(Qh, i * 16 + lr, c, ls);
            fql[i][c] = fragT(Ql, i * 16 + lr, c, ls);
        }
    float rs[4] = {0.f, 0.f, 0.f, 0.f};
    for (int j0 = 0; j0 < N_; j0 += 64) {
        __syncthreads();
        stage_packed64(kb, j0, Kh, Kl, tid);
        __syncthreads();
        bf16x8_t fkh[2], fkl[2];     // A operand: m = j = wv*16+lr
#pragma unroll
        for (int c = 0; c < 2; c++) {
            fkh[c] = fragT(Kh, wv * 16 + lr, c, ls);
            fkl[c] = fragT(Kl, wv * 16 + lr, c, ls);
        }
        int jbase = j0 + wv * 16 + ls * 4;
#pragma unroll
        for (int i = 0; i < 4; i++) {
            f32x4_t s = {0.f, 0.f, 0.f, 0.f};
#pragma unroll
            for (int c = 0; c < 2; c++) {
                s = mfma_bf16(fkh[c], fqh[i][c], s);
                s = mfma_bf16(fkh[c], fql[i][c], s);
                s = mfma_bf16(fkl[c], fqh[i][c], s);
            }
#pragma unroll
            for (int r = 0; r < 4; r++)
                rs[i] += (jbase + r < N_) ? __expf(s[r]) : 0.f;
        }
    }
#pragma unroll
    for (int i = 0; i < 4; i++) {
        float v2 = rs[i];
        v2 += __shfl_xor(v2, 16);
        v2 += __shfl_xor(v2, 32);
        if (ls == 0) red[wv][i * 16 + lr] = v2;
    }
    __syncthreads();
    if (tid < 64) {
        float s = red[0][tid] + red[1][tid] + red[2][tid] + red[3][tid];
        int qn = q0 + tid;
        if (qn < N_) w[(size_t)bh * N_ + qn] = 1.0f / s;
    }
}

// ---------------------------------------------------------------------------
// Pass CS: colsum[bh][j] = sum_q exp(s)*w[q]   (natural S MFMA, split)
// ---------------------------------------------------------------------------
__global__ __launch_bounds__(256) void attn_colsum_mfma(const unsigned* __restrict__ qpk,
                                                        const unsigned* __restrict__ kpk,
                                                        const float* __restrict__ w,
                                                        float* __restrict__ colsum) {
    __shared__ ushort Qh[4096], Ql[4096], Kh[4096], Kl[4096];
    __shared__ float red[4][64];
    __shared__ float wsld[64];
    int bh = blockIdx.y, j0 = blockIdx.x * 64;
    int tid = threadIdx.x, lane = tid & 63, wv = tid >> 6;
    int lr = lane & 15, ls = lane >> 4;
    const unsigned* qb = qpk + (size_t)bh * N_ * D_;
    const unsigned* kb = kpk + (size_t)bh * N_ * D_;
    stage_packed64(kb, j0, Kh, Kl, tid);
    __syncthreads();
    bf16x8_t fkh[4][2], fkl[4][2];   // B operand: n = j = i*16+lr
#pragma unroll
    for (int i = 0; i < 4; i++)
#pragma unroll
        for (int c = 0; c < 2; c++) {
            fkh[i][c] = fragT(Kh, i * 16 + lr, c, ls);
            fkl[i][c] = fragT(Kl, i * 16 + lr, c, ls);
        }
    float cs[4] = {0.f, 0.f, 0.f, 0.f};
    for (int qt = 0; qt < N_; qt += 64) {
        __syncthreads();
        stage_packed64(qb, qt, Qh, Ql, tid);
        if (tid < 64) {
            int qn = qt + tid;
            wsld[tid] = (qn < N_) ? w[(size_t)bh * N_ + qn] : 0.f;
        }
        __syncthreads();
        bf16x8_t fqh[2], fql[2];     // A operand: m = q = wv*16+lr
#pragma unroll
        for (int c = 0; c < 2; c++) {
            fqh[c] = fragT(Qh, wv * 16 + lr, c, ls);
            fql[c] = fragT(Ql, wv * 16 + lr, c, ls);
        }
        float wq[4];
#pragma unroll
        for (int r = 0; r < 4; r++) wq[r] = wsld[wv * 16 + ls * 4 + r];
#pragma unroll
        for (int i = 0; i < 4; i++) {
            f32x4_t s = {0.f, 0.f, 0.f, 0.f};
#pragma unroll
            for (int c = 0; c < 2; c++) {
                s = mfma_bf16(fqh[c], fkh[i][c], s);
                s = mfma_bf16(fql[c], fkh[i][c], s);
                s = mfma_bf16(fqh[c], fkl[i][c], s);
            }
#pragma unroll
            for (int r = 0; r < 4; r++) cs[i] += __expf(s[r]) * wq[r];
        }
    }
#pragma unroll
    for (int i = 0; i < 4; i++) {
        float v2 = cs[i];
        v2 += __shfl_xor(v2, 16);
        v2 += __shfl_xor(v2, 32);
        if (ls == 0) red[wv][i * 16 + lr] = v2;
    }
    __syncthreads();
    if (tid < 64) {
        float t = red[0][tid] + red[1][tid] + red[2][tid] + red[3][tid];
        int jn = j0 + tid;
        if (jn < N_) colsum[(size_t)bh * N_ + jn] = t;
    }
}

// ---------------------------------------------------------------------------
// Top-k per batch: UCB scores + full bitonic sort (desc, ties -> lower index)
// ---------------------------------------------------------------------------
__global__ __launch_bounds__(512) void topk_kernel(const float* __restrict__ colsum,
                                                   const float* __restrict__ ucb_count,
                                                   const int* __restrict__ counter,
                                                   float* __restrict__ kept_out,
                                                   float* __restrict__ kvmask) {
    __shared__ float sv[1024];
    __shared__ int si[1024];
    int b = blockIdx.x, tid = threadIdx.x;
    float lc = logf((float)counter[0] + 1.0f);
    for (int t = tid; t < 1024; t += 512) {
        if (t < N_ - 1) {
            int tok = t + 1;
            float accv = 0.f;
#pragma unroll
            for (int h = 0; h < H_; h++) {
                float csv = colsum[(size_t)(b * H_ + h) * N_ + tok];
                float patch = csv * (1.0f / (float)N_);
                float cnt = ucb_count[h * N_ + tok];
                float expl = sqrtf(lc / (cnt + 1e-6f));
                accv += patch + expl;
            }
            sv[t] = accv * (1.0f / (float)H_);
            si[t] = t;
        } else {
            sv[t] = -INFINITY;
            si[t] = 1 << 20;
        }
    }
    __syncthreads();
    for (int kk = 2; kk <= 1024; kk <<= 1) {
        for (int jj = kk >> 1; jj > 0; jj >>= 1) {
            for (int t = tid; t < 1024; t += 512) {
                int ixj = t ^ jj;
                if (ixj > t) {
                    float v1 = sv[t], v2 = sv[ixj];
                    int i1 = si[t], i2 = si[ixj];
                    bool before21 = (v2 > v1) || (v2 == v1 && i2 < i1);
                    bool dirDesc = ((t & kk) == 0);
                    if (before21 == dirDesc) {
                        sv[t] = v2; sv[ixj] = v1;
                        si[t] = i2; si[ixj] = i1;
                    }
                }
            }
            __syncthreads();
        }
    }
    for (int r = tid; r < KKEEP; r += 512) {
        int tok = si[r] + 1;
        kept_out[b * KKEEP + r] = (float)tok;
        kvmask[b * N_ + tok] = 1.0f;
    }
    if (tid == 0) kvmask[b * N_] = 1.0f;  // CLS always kept
}

// ---------------------------------------------------------------------------
// score_delta[h,n] = (1/B) * count_b(token n kept)   (n=0 -> 0)
// ---------------------------------------------------------------------------
__global__ void score_delta_kernel(const float* __restrict__ kvmask,
                                   float* __restrict__ sd) {
    int idx = blockIdx.x * 256 + threadIdx.x;
    if (idx >= H_ * N_) return;
    int n = idx % N_;
    float d = 0.f;
    if (n != 0) {
#pragma unroll
        for (int b = 0; b < B_; b++) d += kvmask[b * N_ + n];
    }
    sd[idx] = d * (1.0f / (float)B_);
}

// ---------------------------------------------------------------------------
// Pass CTX: masked renormalized context -> bf16 [b,n, h*64+d]
// ---------------------------------------------------------------------------
__global__ __launch_bounds__(256) void attn_ctx_mfma(const unsigned* __restrict__ qpk,
                                                     const unsigned* __restrict__ kpk,
                                                     const ushort* __restrict__ vt,
                                                     const float* __restrict__ w,
                                                     const float* __restrict__ kvmask,
                                                     ushort* __restrict__ ctxb) {
    __shared__ ushort Qh[4096], Ql[4096], Kh[4096], Kl[4096], Vt[4096], Pl[4096];
    __shared__ float wsld[64], mqs[64], mjs[64], red[4][64], inv[64];
    int bh = blockIdx.y, b = bh / H_, h = bh % H_;
    int q0 = blockIdx.x * 64;
    int tid = threadIdx.x, lane = tid & 63, wv = tid >> 6;
    int lr = lane & 15, ls = lane >> 4;
    const unsigned* qbase = qpk + (size_t)bh * N_ * D_;
    const unsigned* kbase = kpk + (size_t)bh * N_ * D_;
    const ushort* vtb = vt + (size_t)bh * 64 * VTS;
    stage_packed64(qbase, q0, Qh, Ql, tid);
    if (tid < 64) {
        int qn = q0 + tid;
        wsld[tid] = (qn < N_) ? w[(size_t)bh * N_ + qn] : 0.f;
        mqs[tid]  = (qn < N_) ? kvmask[b * N_ + qn] : 0.f;
    }
    __syncthreads();
    bf16x8_t fqh[4][2], fql[4][2];
#pragma unroll
    for (int i = 0; i < 4; i++)
#pragma unroll
        for (int c = 0; c < 2; c++) {
            fqh[i][c] = fragT(Qh, i * 16 + lr, c, ls);
            fql[i][c] = fragT(Ql, i * 16 + lr, c, ls);
        }
    float wq[4], mq[4];
#pragma unroll
    for (int i = 0; i < 4; i++) { wq[i] = wsld[i * 16 + lr]; mq[i] = mqs[i * 16 + lr]; }
    f32x4_t acc[4] = {};
    float psums[4] = {0.f, 0.f, 0.f, 0.f};
    for (int j0t = 0; j0t < N_; j0t += 64) {
        __syncthreads();
        stage_packed64(kbase, j0t, Kh, Kl, tid);
        stage_vt(vtb, j0t, Vt, tid);
        if (tid < 64) {
            int jn = j0t + tid;
            mjs[tid] = (jn < N_) ? kvmask[b * N_ + jn] : 0.f;
        }
        __syncthreads();
        bf16x8_t fkh[2], fkl[2];
#pragma unroll
        for (int c = 0; c < 2; c++) {
            fkh[c] = fragT(Kh, wv * 16 + lr, c, ls);
            fkl[c] = fragT(Kl, wv * 16 + lr, c, ls);
        }
        int jloc = wv * 16 + ls * 4;
#pragma unroll
        for (int i = 0; i < 4; i++) {
            f32x4_t s = {0.f, 0.f, 0.f, 0.f};
#pragma unroll
            for (int c = 0; c < 2; c++) {
                s = mfma_bf16(fkh[c], fqh[i][c], s);
                s = mfma_bf16(fkh[c], fql[i][c], s);
                s = mfma_bf16(fkl[c], fqh[i][c], s);
            }
            unsigned int pk[4];
            float wqi = wq[i], mqi = mq[i];
#pragma unroll
            for (int r = 0; r < 4; r++) {
                int j = j0t + jloc + r;
                float mj = mjs[jloc + r];
                float p = (j < N_) ? __expf(s[r]) * wqi : 0.f;
                p = (mqi > 0.5f || mj > 0.5f) ? p : 0.f;
                psums[i] += p;
                pk[r] = bf16rne(p);
            }
            int row = i * 16 + lr;
            int slot = ((wv << 1) + (ls >> 1)) ^ (row & 7);
            *(uint2*)&Pl[(row << 6) + (slot << 3) + ((ls & 1) << 2)] =
                make_uint2(pk[0] | (pk[1] << 16), pk[2] | (pk[3] << 16));
        }
        __syncthreads();
        bf16x8_t fv[2];
#pragma unroll
        for (int c = 0; c < 2; c++) fv[c] = fragT(Vt, wv * 16 + lr, c, ls);
#pragma unroll
        for (int i = 0; i < 4; i++) {
            bf16x8_t fp0 = fragT(Pl, i * 16 + lr, 0, ls);
            bf16x8_t fp1 = fragT(Pl, i * 16 + lr, 1, ls);
            acc[i] = mfma_bf16(fv[0], fp0, acc[i]);
            acc[i] = mfma_bf16(fv[1], fp1, acc[i]);
        }
    }
#pragma unroll
    for (int i = 0; i < 4; i++) {
        float v2 = psums[i];
        v2 += __shfl_xor(v2, 16);
        v2 += __shfl_xor(v2, 32);
        if (ls == 0) red[wv][i * 16 + lr] = v2;
    }
    __syncthreads();
    if (tid < 64) {
        float t = red[0][tid] + red[1][tid] + red[2][tid] + red[3][tid];
        inv[tid] = 1.0f / (t + 1e-8f);
    }
    __syncthreads();
#pragma unroll
    for (int i = 0; i < 4; i++) {
        int qn = q0 + i * 16 + lr;
        if (qn < N_) {
            float rn = inv[i * 16 + lr];
            unsigned int h0 = bf16rne(acc[i][0] * rn);
            unsigned int h1 = bf16rne(acc[i][1] * rn);
            unsigned int h2 = bf16rne(acc[i][2] * rn);
            unsigned int h3 = bf16rne(acc[i][3] * rn);
            *(uint2*)&ctxb[((size_t)(b * N_ + qn)) * C_ + h * D_ + wv * 16 + ls * 4] =
                make_uint2(h0 | (h1 << 16), h2 | (h3 << 16));
        }
    }
}

// ---------------------------------------------------------------------------
// MFMA GEMM 2 (plain bf16, prepacked W): out = context_bf16 @ Wproj^T + bproj
// ---------------------------------------------------------------------------
__global__ __launch_bounds__(256) void gemm_proj_mfma(const ushort* __restrict__ Actx,
                                                      const ushort* __restrict__ Wb,
                                                      const float* __restrict__ bias,
                                                      float* __restrict__ out) {
    __shared__ ushort Ab[128 * 32], Bb[128 * 32];
    const int tid = threadIdx.x;
    const int lane = tid & 63, wave = tid >> 6;
    const int wr = wave >> 1, wc = wave & 1;
    const int lr = lane & 15, ls = lane >> 4;
    const int m0 = blockIdx.y * 128, n0 = blockIdx.x * 128;
    const int srow = tid >> 1, shalf = tid & 1;
    const int arow = min(m0 + srow, M_TOT - 1);
    const ushort* aptr = Actx + (size_t)arow * C_ + shalf * 16;
    const ushort* bptr = Wb + (size_t)(n0 + srow) * C_ + shalf * 16;
    const int swz = (srow >> 1) & 3;
    const int sidx = srow * 32;
    const int p0 = (shalf * 2 + 0) ^ swz, p1 = (shalf * 2 + 1) ^ swz;
    f32x4_t acc[4][4] = {};
#pragma unroll 1
    for (int k0 = 0; k0 < C_; k0 += 32) {
        __syncthreads();
        {
            u32x4_t c0 = *(const u32x4_t*)(aptr + k0);
            u32x4_t c1 = *(const u32x4_t*)(aptr + k0 + 8);
            *(u32x4_t*)&Ab[sidx + p0 * 8] = c0;
            *(u32x4_t*)&Ab[sidx + p1 * 8] = c1;
        }
        {
            u32x4_t c0 = *(const u32x4_t*)(bptr + k0);
            u32x4_t c1 = *(const u32x4_t*)(bptr + k0 + 8);
            *(u32x4_t*)&Bb[sidx + p0 * 8] = c0;
            *(u32x4_t*)&Bb[sidx + p1 * 8] = c1;
        }
        __syncthreads();
        bf16x8_t fa[4], fb[4];
#pragma unroll
        for (int i = 0; i < 4; i++) {
            int rowA = wr * 64 + i * 16 + lr;
            int pa = ls ^ ((rowA >> 1) & 3);
            fa[i] = __builtin_bit_cast(bf16x8_t, *(const u32x4_t*)&Ab[rowA * 32 + pa * 8]);
            int rowB = wc * 64 + i * 16 + lr;
            int pb = ls ^ ((rowB >> 1) & 3);
            fb[i] = __builtin_bit_cast(bf16x8_t, *(const u32x4_t*)&Bb[rowB * 32 + pb * 8]);
        }
#pragma unroll
        for (int i = 0; i < 4; i++)
#pragma unroll
            for (int j = 0; j < 4; j++)
                acc[i][j] = mfma_bf16(fa[i], fb[j], acc[i][j]);
    }
#pragma unroll
    for (int j = 0; j < 4; j++) {
        int ng = n0 + wc * 64 + j * 16 + lr;
        float bb = bias[ng];
#pragma unroll
        for (int i = 0; i < 4; i++) {
            int mg0 = m0 + wr * 64 + i * 16 + ls * 4;
#pragma unroll
            for (int r = 0; r < 4; r++) {
                int m = mg0 + r;
                if (m < M_TOT) out[(size_t)m * C_ + ng] = acc[i][j][r] + bb;
            }
        }
    }
}

// ---------------------------------------------------------------------------
extern "C" void kernel_launch(void* const* d_in, const int* in_sizes, int n_in,
                              void* d_out, int out_size, void* d_ws, size_t ws_size,
                              hipStream_t stream) {
    const float* x     = (const float*)d_in[0];
    const float* ucb   = (const float*)d_in[1];
    const float* Wqkv  = (const float*)d_in[2];
    const float* Wproj = (const float*)d_in[3];
    const float* bproj = (const float*)d_in[4];
    const int*   counter = (const int*)d_in[5];

    const size_t SZ   = (size_t)B_ * H_ * N_ * D_;  // 7,090,176 (== M_TOT*C_)
    const size_t BHN  = (size_t)B_ * H_ * N_;       // 110,784
    const size_t XPL  = (size_t)(73 * 128) * C_;    // 7,176,192 (padded M x K)
    const size_t WPL  = (size_t)3 * C_ * C_;        // 1,769,472
    const size_t WPJ  = (size_t)C_ * C_;            // 589,824
    const size_t VTSZ = (size_t)B_ * H_ * D_ * VTS; // 7,864,320

    unsigned* qpk  = (unsigned*)d_ws;
    unsigned* kpk  = qpk + SZ;
    ushort*   XplH = (ushort*)(kpk + SZ);
    ushort*   XplL = XplH + XPL;
    ushort*   ctxb = XplH;                 // alias: planes dead after gemm_qkv
    ushort*   WplH = XplL + XPL;
    ushort*   WplL = WplH + WPL;
    ushort*   Wpjb = WplL + WPL;
    ushort*   vt   = Wpjb + WPJ;
    float*    w    = (float*)(vt + VTSZ);
    float*    colsum = w + BHN;
    float*    kvmask = colsum + BHN;
    size_t need = ((char*)(kvmask + (size_t)B_ * N_)) - (char*)d_ws;
    if (ws_size < need) {
        fprintf(stderr, "kernel_launch: ws too small, need %zu have %zu\n",
                need, ws_size);
        return;
    }

    float* out  = (float*)d_out;
    float* sd   = out + (size_t)B_ * N_ * C_;
    float* kept = sd + (size_t)H_ * N_;

    hipMemsetAsync(kvmask, 0, (size_t)B_ * N_ * sizeof(float), stream);
    hipMemsetAsync(vt, 0, VTSZ * sizeof(ushort), stream);

    pack_tiles_kernel<<<73 * NKT, 256, 0, stream>>>(x, XplH, XplL, M_TOT);
    pack_tiles_kernel<<<18 * NKT, 256, 0, stream>>>(Wqkv, WplH, WplL, 3 * C_);
    pack_rne_kernel<<<(int)(WPJ / 8 / 256), 256, 0, stream>>>(Wproj, Wpjb, (int)(WPJ / 8));

    gemm_qkv_mfma<<<dim3(18, 73), 256, 0, stream>>>(XplH, XplL, WplH, WplL, qpk, kpk, vt);
    attn_rowsum_mfma<<<dim3(10, B_ * H_), 256, 0, stream>>>(qpk, kpk, w);
    attn_colsum_mfma<<<dim3(10, B_ * H_), 256, 0, stream>>>(qpk, kpk, w, colsum);
    topk_kernel<<<B_, 512, 0, stream>>>(colsum, ucb, counter, kept, kvmask);
    score_delta_kernel<<<(H_ * N_ + 255) / 256, 256, 0, stream>>>(kvmask, sd);
    attn_ctx_mfma<<<dim3(10, B_ * H_), 256, 0, stream>>>(qpk, kpk, vt, w, kvmask, ctxb);
    gemm_proj_mfma<<<dim3(6, 73), 256, 0, stream>>>(ctxb, Wpjb, bproj, out);
}

// Round 7
// 372.374 us; speedup vs baseline: 1.2130x; 1.2130x over previous
//
#include <hip/hip_runtime.h>
#include <cstdio>
#include <cstdint>

// Problem constants
#define B_    16
#define N_    577
#define C_    768
#define H_    12
#define D_    64
#define KKEEP 288            // max(1, int(576*0.5))
#define SCALE 0.125f         // 64^-0.5 (exact power of 2)
#define M_TOT (B_ * N_)      // 9232
#define VTS   640            // vt row stride (>= 10*64, 16B-aligned)
#define NKT   24             // K tiles (768/32)

typedef __bf16 bf16x8_t __attribute__((ext_vector_type(8)));
typedef float  f32x4_t  __attribute__((ext_vector_type(4)));
typedef unsigned int u32x4_t __attribute__((ext_vector_type(4)));

__device__ __forceinline__ f32x4_t mfma_bf16(bf16x8_t a, bf16x8_t b, f32x4_t c) {
    return __builtin_amdgcn_mfma_f32_16x16x32_bf16(a, b, c, 0, 0, 0);
}

// async global->LDS, 16B per lane (lds dest = wave-uniform base + lane*16)
__device__ __forceinline__ void gload16(const ushort* g, ushort* l) {
    __builtin_amdgcn_global_load_lds(
        (const __attribute__((address_space(1))) void*)g,
        (__attribute__((address_space(3))) void*)l, 16, 0, 0);
}

// RTZ split of f32 into two bf16 bit patterns (x ~= hi + lo, err ~2^-16 |x|)
__device__ __forceinline__ void splitf(float x, unsigned int &hi, unsigned int &lo) {
    unsigned int u = __float_as_uint(x);
    hi = u >> 16;
    float r = x - __uint_as_float(u & 0xffff0000u);
    lo = __float_as_uint(r) >> 16;
}
__device__ __forceinline__ unsigned int bf16rne(float x) {
    unsigned int u = __float_as_uint(x);
    return (u + 0x7fffu + ((u >> 16) & 1u)) >> 16;
}
// packed-split pair merges: p = hi|lo<<16 per element
__device__ __forceinline__ unsigned hp(unsigned a, unsigned b) { return (a & 0xffffu) | (b << 16); }
__device__ __forceinline__ unsigned lp(unsigned a, unsigned b) { return (a >> 16) | (b & 0xffff0000u); }

__device__ __forceinline__ void unpack16(const unsigned* p, u32x4_t &hc0, u32x4_t &hc1,
                                         u32x4_t &lc0, u32x4_t &lc1) {
    hc0 = (u32x4_t){hp(p[0], p[1]), hp(p[2], p[3]), hp(p[4], p[5]), hp(p[6], p[7])};
    hc1 = (u32x4_t){hp(p[8], p[9]), hp(p[10], p[11]), hp(p[12], p[13]), hp(p[14], p[15])};
    lc0 = (u32x4_t){lp(p[0], p[1]), lp(p[2], p[3]), lp(p[4], p[5]), lp(p[6], p[7])};
    lc1 = (u32x4_t){lp(p[8], p[9]), lp(p[10], p[11]), lp(p[12], p[13]), lp(p[14], p[15])};
}

// ---------------------------------------------------------------------------
// Prepass: pack f32 [nrows x 768] into split hi/lo bf16 planes in TILED,
// PRE-SWIZZLED layout (matches fragT's read swizzle; see round-6 notes).
// ---------------------------------------------------------------------------
__global__ __launch_bounds__(256) void pack_tiles_kernel(const float* __restrict__ src,
                                                         ushort* __restrict__ dH,
                                                         ushort* __restrict__ dL,
                                                         int nrows) {
    int tile = blockIdx.x;
    int kt = tile % NKT, mt = tile / NKT;
    int w = threadIdx.x;
    int row = w >> 1, h = w & 1;
    int m = mt * 128 + row;
    int sw = (row >> 1) & 3;
    float f[16];
    if (m < nrows) {
        const float* s = src + (size_t)m * C_ + kt * 32;
        int sa = (2 * h) ^ sw, sb = (2 * h + 1) ^ sw;   // logical slots
        *(float4*)&f[0]  = *(const float4*)(s + sa * 8);
        *(float4*)&f[4]  = *(const float4*)(s + sa * 8 + 4);
        *(float4*)&f[8]  = *(const float4*)(s + sb * 8);
        *(float4*)&f[12] = *(const float4*)(s + sb * 8 + 4);
    } else {
#pragma unroll
        for (int i = 0; i < 16; i++) f[i] = 0.f;
    }
    unsigned hi[16], lo[16];
#pragma unroll
    for (int i = 0; i < 16; i++) splitf(f[i], hi[i], lo[i]);
    u32x4_t h0 = {hi[0] | (hi[1] << 16), hi[2] | (hi[3] << 16),
                  hi[4] | (hi[5] << 16), hi[6] | (hi[7] << 16)};
    u32x4_t h1 = {hi[8] | (hi[9] << 16), hi[10] | (hi[11] << 16),
                  hi[12] | (hi[13] << 16), hi[14] | (hi[15] << 16)};
    u32x4_t l0 = {lo[0] | (lo[1] << 16), lo[2] | (lo[3] << 16),
                  lo[4] | (lo[5] << 16), lo[6] | (lo[7] << 16)};
    u32x4_t l1 = {lo[8] | (lo[9] << 16), lo[10] | (lo[11] << 16),
                  lo[12] | (lo[13] << 16), lo[14] | (lo[15] << 16)};
    size_t dbase = (size_t)tile * 4096 + row * 32;
    *(u32x4_t*)&dH[dbase + (2 * h) * 8]     = h0;
    *(u32x4_t*)&dH[dbase + (2 * h + 1) * 8] = h1;
    *(u32x4_t*)&dL[dbase + (2 * h) * 8]     = l0;
    *(u32x4_t*)&dL[dbase + (2 * h + 1) * 8] = l1;
}

// Prepass: f32 -> bf16 RNE, 8 elems/thread
__global__ __launch_bounds__(256) void pack_rne_kernel(const float* __restrict__ src,
                                                       ushort* __restrict__ dst, int n8) {
    int i = blockIdx.x * 256 + threadIdx.x;
    if (i >= n8) return;
    float4 f0 = ((const float4*)src)[2 * i];
    float4 f1 = ((const float4*)src)[2 * i + 1];
    u32x4_t o = {bf16rne(f0.x) | (bf16rne(f0.y) << 16),
                 bf16rne(f0.z) | (bf16rne(f0.w) << 16),
                 bf16rne(f1.x) | (bf16rne(f1.y) << 16),
                 bf16rne(f1.z) | (bf16rne(f1.w) << 16)};
    *(u32x4_t*)&dst[(size_t)i * 8] = o;
}

// ===========================================================================
// 64x64 bf16 LDS tiles: 64 ushort/row, 8 slots of 8; phys slot = logical^(row&7)
// ===========================================================================
__device__ __forceinline__ bf16x8_t fragT(const ushort* H, int row, int c, int ls) {
    int phys = ((c << 2) + ls) ^ (row & 7);
    return __builtin_bit_cast(bf16x8_t, *(const u32x4_t*)&H[(row << 6) + (phys << 3)]);
}

// stage 64x64 packed-split tile (rows row0.. from [N][64] u32) into Hh/Hl LDS
__device__ __forceinline__ void stage_packed64(const unsigned* __restrict__ base, int row0,
                                               ushort* Hh, ushort* Hl, int tid) {
    int r = tid >> 2, qd = tid & 3;
    int rn = row0 + r;
    unsigned p[16];
    if (rn < N_) {
        const unsigned* src = base + (size_t)rn * D_ + qd * 16;
        *(u32x4_t*)&p[0]  = *(const u32x4_t*)(src);
        *(u32x4_t*)&p[4]  = *(const u32x4_t*)(src + 4);
        *(u32x4_t*)&p[8]  = *(const u32x4_t*)(src + 8);
        *(u32x4_t*)&p[12] = *(const u32x4_t*)(src + 12);
    } else {
#pragma unroll
        for (int i = 0; i < 16; i++) p[i] = 0;
    }
    u32x4_t hc0, hc1, lc0, lc1;
    unpack16(p, hc0, hc1, lc0, lc1);
    int s0 = (2 * qd) ^ (r & 7), s1 = (2 * qd + 1) ^ (r & 7);
    *(u32x4_t*)&Hh[(r << 6) + (s0 << 3)] = hc0;
    *(u32x4_t*)&Hh[(r << 6) + (s1 << 3)] = hc1;
    *(u32x4_t*)&Hl[(r << 6) + (s0 << 3)] = lc0;
    *(u32x4_t*)&Hl[(r << 6) + (s1 << 3)] = lc1;
}

// stage 64x64 bf16 tile from vt (rows = d, row stride VTS), cols j0..j0+63
__device__ __forceinline__ void stage_vt(const ushort* __restrict__ vtb, int j0,
                                         ushort* Vt, int tid) {
    int r = tid >> 2, qd = tid & 3;
    const ushort* src = vtb + (size_t)r * VTS + j0 + qd * 16;
    u32x4_t c0 = *(const u32x4_t*)(src);
    u32x4_t c1 = *(const u32x4_t*)(src + 8);
    int s0 = (2 * qd) ^ (r & 7), s1 = (2 * qd + 1) ^ (r & 7);
    *(u32x4_t*)&Vt[(r << 6) + (s0 << 3)] = c0;
    *(u32x4_t*)&Vt[(r << 6) + (s1 << 3)] = c1;
}

// ---------------------------------------------------------------------------
// MFMA GEMM 1a (q,k columns): 2-phase double-buffered counted-vmcnt pipeline.
// outputs: qpk/kpk packed-split u32 [B,H,N,D] (q pre-scaled by SCALE)
// ---------------------------------------------------------------------------
__global__ __launch_bounds__(256) void gemm_qk_mfma(const ushort* __restrict__ XplH,
                                                    const ushort* __restrict__ XplL,
                                                    const ushort* __restrict__ WplH,
                                                    const ushort* __restrict__ WplL,
                                                    unsigned* __restrict__ qpk,
                                                    unsigned* __restrict__ kpk) {
    __shared__ ushort Ah[2][4096], Al[2][4096], Bh[2][4096], Bl[2][4096];
    const int tid = threadIdx.x;
    const int lane = tid & 63, wave = tid >> 6;
    const int wr = wave >> 1, wc = wave & 1;
    const int lr = lane & 15, ls = lane >> 4;
    const int m0 = blockIdx.y * 128, n0 = blockIdx.x * 128;
    const int s = n0 / C_;          // 0=q, 1=k (block-uniform)
    const int o0 = wave * 1024, o1 = o0 + 512;   // ushort offsets, 2KB/wave
    const int la = lane * 8;
    const size_t abase = (size_t)blockIdx.y * NKT * 4096;
    const size_t bbase = (size_t)blockIdx.x * NKT * 4096;
    f32x4_t acc[4][4] = {};

    auto stage = [&](int buf, int kt) {
        const size_t ta = abase + (size_t)kt * 4096;
        const size_t tb = bbase + (size_t)kt * 4096;
        gload16(XplH + ta + o0 + la, &Ah[buf][o0]);
        gload16(XplH + ta + o1 + la, &Ah[buf][o1]);
        gload16(XplL + ta + o0 + la, &Al[buf][o0]);
        gload16(XplL + ta + o1 + la, &Al[buf][o1]);
        gload16(WplH + tb + o0 + la, &Bh[buf][o0]);
        gload16(WplH + tb + o1 + la, &Bh[buf][o1]);
        gload16(WplL + tb + o0 + la, &Bl[buf][o0]);
        gload16(WplL + tb + o1 + la, &Bl[buf][o1]);
    };
    stage(0, 0);
#pragma unroll 1
    for (int kt = 0; kt < NKT; ++kt) {
        const int cur = kt & 1;
        if (kt + 1 < NKT) {
            stage(cur ^ 1, kt + 1);
            asm volatile("s_waitcnt vmcnt(8)" ::: "memory");
        } else {
            asm volatile("s_waitcnt vmcnt(0)" ::: "memory");
        }
        __builtin_amdgcn_sched_barrier(0);
        __builtin_amdgcn_s_barrier();
        __builtin_amdgcn_sched_barrier(0);
        bf16x8_t fah[4], fal[4], fbh[4], fbl[4];
#pragma unroll
        for (int i = 0; i < 4; i++) {
            int rowA = wr * 64 + i * 16 + lr;
            int pa = ls ^ ((rowA >> 1) & 3);
            fah[i] = __builtin_bit_cast(bf16x8_t, *(const u32x4_t*)&Ah[cur][rowA * 32 + pa * 8]);
            fal[i] = __builtin_bit_cast(bf16x8_t, *(const u32x4_t*)&Al[cur][rowA * 32 + pa * 8]);
            int rowB = wc * 64 + i * 16 + lr;
            int pb = ls ^ ((rowB >> 1) & 3);
            fbh[i] = __builtin_bit_cast(bf16x8_t, *(const u32x4_t*)&Bh[cur][rowB * 32 + pb * 8]);
            fbl[i] = __builtin_bit_cast(bf16x8_t, *(const u32x4_t*)&Bl[cur][rowB * 32 + pb * 8]);
        }
#pragma unroll
        for (int i = 0; i < 4; i++)
#pragma unroll
            for (int j = 0; j < 4; j++) {
                acc[i][j] = mfma_bf16(fah[i], fbh[j], acc[i][j]);
                acc[i][j] = mfma_bf16(fah[i], fbl[j], acc[i][j]);
                acc[i][j] = mfma_bf16(fal[i], fbh[j], acc[i][j]);
            }
        if (kt + 1 < NKT) {
            __builtin_amdgcn_sched_barrier(0);
            __builtin_amdgcn_s_barrier();
        }
    }
    unsigned* dst = (s == 1) ? kpk : qpk;
    const float sc = (s == 0) ? SCALE : 1.0f;
#pragma unroll
    for (int j = 0; j < 4; j++) {
        int ng = n0 + wc * 64 + j * 16 + lr;
        int hh = (ng % C_) / D_;
        int d = ng % D_;
#pragma unroll
        for (int i = 0; i < 4; i++) {
            int mg0 = m0 + wr * 64 + i * 16 + ls * 4;
#pragma unroll
            for (int r = 0; r < 4; r++) {
                int m = mg0 + r;
                if (m < M_TOT) {
                    int b = m / N_, n = m % N_;
                    unsigned hi, lo;
                    splitf(acc[i][j][r] * sc, hi, lo);
                    dst[((size_t)(b * H_ + hh) * N_ + n) * D_ + d] = hi | (lo << 16);
                }
            }
        }
    }
}

// ---------------------------------------------------------------------------
// MFMA GEMM 1b (v columns): 2-term split (X*Whi only needs Bh), same pipeline.
// output: vt bf16 transposed [bh*64+d][VTS]
// ---------------------------------------------------------------------------
__global__ __launch_bounds__(256) void gemm_v_mfma(const ushort* __restrict__ XplH,
                                                   const ushort* __restrict__ XplL,
                                                   const ushort* __restrict__ WplH,
                                                   ushort* __restrict__ vt) {
    __shared__ ushort Ah[2][4096], Al[2][4096], Bh[2][4096];
    const int tid = threadIdx.x;
    const int lane = tid & 63, wave = tid >> 6;
    const int wr = wave >> 1, wc = wave & 1;
    const int lr = lane & 15, ls = lane >> 4;
    const int m0 = blockIdx.y * 128, n0v = blockIdx.x * 128;  // v-relative col
    const int o0 = wave * 1024, o1 = o0 + 512;
    const int la = lane * 8;
    const size_t abase = (size_t)blockIdx.y * NKT * 4096;
    const size_t bbase = (size_t)(12 + blockIdx.x) * NKT * 4096;
    f32x4_t acc[4][4] = {};

    auto stage = [&](int buf, int kt) {
        const size_t ta = abase + (size_t)kt * 4096;
        const size_t tb = bbase + (size_t)kt * 4096;
        gload16(XplH + ta + o0 + la, &Ah[buf][o0]);
        gload16(XplH + ta + o1 + la, &Ah[buf][o1]);
        gload16(XplL + ta + o0 + la, &Al[buf][o0]);
        gload16(XplL + ta + o1 + la, &Al[buf][o1]);
        gload16(WplH + tb + o0 + la, &Bh[buf][o0]);
        gload16(WplH + tb + o1 + la, &Bh[buf][o1]);
    };
    stage(0, 0);
#pragma unroll 1
    for (int kt = 0; kt < NKT; ++kt) {
        const int cur = kt & 1;
        if (kt + 1 < NKT) {
            stage(cur ^ 1, kt + 1);
            asm volatile("s_waitcnt vmcnt(6)" ::: "memory");
        } else {
            asm volatile("s_waitcnt vmcnt(0)" ::: "memory");
        }
        __builtin_amdgcn_sched_barrier(0);
        __builtin_amdgcn_s_barrier();
        __builtin_amdgcn_sched_barrier(0);
        bf16x8_t fah[4], fal[4], fbh[4];
#pragma unroll
        for (int i = 0; i < 4; i++) {
            int rowA = wr * 64 + i * 16 + lr;
            int pa = ls ^ ((rowA >> 1) & 3);
            fah[i] = __builtin_bit_cast(bf16x8_t, *(const u32x4_t*)&Ah[cur][rowA * 32 + pa * 8]);
            fal[i] = __builtin_bit_cast(bf16x8_t, *(const u32x4_t*)&Al[cur][rowA * 32 + pa * 8]);
            int rowB = wc * 64 + i * 16 + lr;
            int pb = ls ^ ((rowB >> 1) & 3);
            fbh[i] = __builtin_bit_cast(bf16x8_t, *(const u32x4_t*)&Bh[cur][rowB * 32 + pb * 8]);
        }
#pragma unroll
        for (int i = 0; i < 4; i++)
#pragma unroll
            for (int j = 0; j < 4; j++) {
                acc[i][j] = mfma_bf16(fah[i], fbh[j], acc[i][j]);
                acc[i][j] = mfma_bf16(fal[i], fbh[j], acc[i][j]);
            }
        if (kt + 1 < NKT) {
            __builtin_amdgcn_sched_barrier(0);
            __builtin_amdgcn_s_barrier();
        }
    }
#pragma unroll
    for (int j = 0; j < 4; j++) {
        int ng = n0v + wc * 64 + j * 16 + lr;   // < 768
        int hh = ng / D_;
        int d = ng % D_;
#pragma unroll
        for (int i = 0; i < 4; i++) {
            int mg0 = m0 + wr * 64 + i * 16 + ls * 4;
#pragma unroll
            for (int r = 0; r < 4; r++) {
                int m = mg0 + r;
                if (m < M_TOT) {
                    int b = m / N_, n = m % N_;
                    vt[((size_t)(b * H_ + hh) * D_ + d) * VTS + n] =
                        (ushort)bf16rne(acc[i][j][r]);
                }
            }
        }
    }
}

// ---------------------------------------------------------------------------
// Pass R: w[bh][q] = 1 / sum_j exp(s)   (swapped S^T MFMA, split, q prescaled)
// ---------------------------------------------------------------------------
__global__ __launch_bounds__(256) void attn_rowsum_mfma(const unsigned* __restrict__ qpk,
                                                        const unsigned* __restrict__ kpk,
                                                        float* __restrict__ w) {
    __shared__ ushort Qh[4096], Ql[4096], Kh[4096], Kl[4096];
    __shared__ float red[4][64];
    int bh = blockIdx.y, q0 = blockIdx.x * 64;
    int tid = threadIdx.x, lane = tid & 63, wv = tid >> 6;
    int lr = lane & 15, ls = lane >> 4;
    const unsigned* qb = qpk + (size_t)bh * N_ * D_;
    const unsigned* kb = kpk + (size_t)bh * N_ * D_;
    stage_packed64(qb, q0, Qh, Ql, tid);
    __syncthreads();
    bf16x8_t fqh[4][2], fql[4][2];   // B operand: n = q = i*16+lr
#pragma unroll
    for (int i = 0; i < 4; i++)
#pragma unroll
        for (int c = 0; c < 2; c++) {
            fqh[i][c] = fragT(Qh, i * 16 + lr, c, ls);
            fql[i][c] = fragT(Ql, i * 16 + lr, c, ls);
        }
    float rs[4] = {0.f, 0.f, 0.f, 0.f};
    for (int j0 = 0; j0 < N_; j0 += 64) {
        __syncthreads();
        stage_packed64(kb, j0, Kh, Kl, tid);
        __syncthreads();
        bf16x8_t fkh[2], fkl[2];     // A operand: m = j = wv*16+lr
#pragma unroll
        for (int c = 0; c < 2; c++) {
            fkh[c] = fragT(Kh, wv * 16 + lr, c, ls);
            fkl[c] = fragT(Kl, wv * 16 + lr, c, ls);
        }
        int jbase = j0 + wv * 16 + ls * 4;
#pragma unroll
        for (int i = 0; i < 4; i++) {
            f32x4_t s = {0.f, 0.f, 0.f, 0.f};
#pragma unroll
            for (int c = 0; c < 2; c++) {
                s = mfma_bf16(fkh[c], fqh[i][c], s);
                s = mfma_bf16(fkh[c], fql[i][c], s);
                s = mfma_bf16(fkl[c], fqh[i][c], s);
            }
#pragma unroll
            for (int r = 0; r < 4; r++)
                rs[i] += (jbase + r < N_) ? __expf(s[r]) : 0.f;
        }
    }
#pragma unroll
    for (int i = 0; i < 4; i++) {
        float v2 = rs[i];
        v2 += __shfl_xor(v2, 16);
        v2 += __shfl_xor(v2, 32);
        if (ls == 0) red[wv][i * 16 + lr] = v2;
    }
    __syncthreads();
    if (tid < 64) {
        float s = red[0][tid] + red[1][tid] + red[2][tid] + red[3][tid];
        int qn = q0 + tid;
        if (qn < N_) w[(size_t)bh * N_ + qn] = 1.0f / s;
    }
}

// ---------------------------------------------------------------------------
// Pass CS: colsum[bh][j] = sum_q exp(s)*w[q]   (natural S MFMA, split)
// ---------------------------------------------------------------------------
__global__ __launch_bounds__(256) void attn_colsum_mfma(const unsigned* __restrict__ qpk,
                                                        const unsigned* __restrict__ kpk,
                                                        const float* __restrict__ w,
                                                        float* __restrict__ colsum) {
    __shared__ ushort Qh[4096], Ql[4096], Kh[4096], Kl[4096];
    __shared__ float red[4][64];
    __shared__ float wsld[64];
    int bh = blockIdx.y, j0 = blockIdx.x * 64;
    int tid = threadIdx.x, lane = tid & 63, wv = tid >> 6;
    int lr = lane & 15, ls = lane >> 4;
    const unsigned* qb = qpk + (size_t)bh * N_ * D_;
    const unsigned* kb = kpk + (size_t)bh * N_ * D_;
    stage_packed64(kb, j0, Kh, Kl, tid);
    __syncthreads();
    bf16x8_t fkh[4][2], fkl[4][2];   // B operand: n = j = i*16+lr
#pragma unroll
    for (int i = 0; i < 4; i++)
#pragma unroll
        for (int c = 0; c < 2; c++) {
            fkh[i][c] = fragT(Kh, i * 16 + lr, c, ls);
            fkl[i][c] = fragT(Kl, i * 16 + lr, c, ls);
        }
    float cs[4] = {0.f, 0.f, 0.f, 0.f};
    for (int qt = 0; qt < N_; qt += 64) {
        __syncthreads();
        stage_packed64(qb, qt, Qh, Ql, tid);
        if (tid < 64) {
            int qn = qt + tid;
            wsld[tid] = (qn < N_) ? w[(size_t)bh * N_ + qn] : 0.f;
        }
        __syncthreads();
        bf16x8_t fqh[2], fql[2];     // A operand: m = q = wv*16+lr
#pragma unroll
        for (int c = 0; c < 2; c++) {
            fqh[c] = fragT(Qh, wv * 16 + lr, c, ls);
            fql[c] = fragT(Ql, wv * 16 + lr, c, ls);
        }
        float wq[4];
#pragma unroll
        for (int r = 0; r < 4; r++) wq[r] = wsld[wv * 16 + ls * 4 + r];
#pragma unroll
        for (int i = 0; i < 4; i++) {
            f32x4_t s = {0.f, 0.f, 0.f, 0.f};
#pragma unroll
            for (int c = 0; c < 2; c++) {
                s = mfma_bf16(fqh[c], fkh[i][c], s);
                s = mfma_bf16(fql[c], fkh[i][c], s);
                s = mfma_bf16(fqh[c], fkl[i][c], s);
            }
#pragma unroll
            for (int r = 0; r < 4; r++) cs[i] += __expf(s[r]) * wq[r];
        }
    }
#pragma unroll
    for (int i = 0; i < 4; i++) {
        float v2 = cs[i];
        v2 += __shfl_xor(v2, 16);
        v2 += __shfl_xor(v2, 32);
        if (ls == 0) red[wv][i * 16 + lr] = v2;
    }
    __syncthreads();
    if (tid < 64) {
        float t = red[0][tid] + red[1][tid] + red[2][tid] + red[3][tid];
        int jn = j0 + tid;
        if (jn < N_) colsum[(size_t)bh * N_ + jn] = t;
    }
}

// ---------------------------------------------------------------------------
// Top-k per batch: UCB scores + full bitonic sort (desc, ties -> lower index)
// ---------------------------------------------------------------------------
__global__ __launch_bounds__(512) void topk_kernel(const float* __restrict__ colsum,
                                                   const float* __restrict__ ucb_count,
                                                   const int* __restrict__ counter,
                                                   float* __restrict__ kept_out,
                                                   float* __restrict__ kvmask) {
    __shared__ float sv[1024];
    __shared__ int si[1024];
    int b = blockIdx.x, tid = threadIdx.x;
    float lc = logf((float)counter[0] + 1.0f);
    for (int t = tid; t < 1024; t += 512) {
        if (t < N_ - 1) {
            int tok = t + 1;
            float accv = 0.f;
#pragma unroll
            for (int h = 0; h < H_; h++) {
                float csv = colsum[(size_t)(b * H_ + h) * N_ + tok];
                float patch = csv * (1.0f / (float)N_);
                float cnt = ucb_count[h * N_ + tok];
                float expl = sqrtf(lc / (cnt + 1e-6f));
                accv += patch + expl;
            }
            sv[t] = accv * (1.0f / (float)H_);
            si[t] = t;
        } else {
            sv[t] = -INFINITY;
            si[t] = 1 << 20;
        }
    }
    __syncthreads();
    for (int kk = 2; kk <= 1024; kk <<= 1) {
        for (int jj = kk >> 1; jj > 0; jj >>= 1) {
            for (int t = tid; t < 1024; t += 512) {
                int ixj = t ^ jj;
                if (ixj > t) {
                    float v1 = sv[t], v2 = sv[ixj];
                    int i1 = si[t], i2 = si[ixj];
                    bool before21 = (v2 > v1) || (v2 == v1 && i2 < i1);
                    bool dirDesc = ((t & kk) == 0);
                    if (before21 == dirDesc) {
                        sv[t] = v2; sv[ixj] = v1;
                        si[t] = i2; si[ixj] = i1;
                    }
                }
            }
            __syncthreads();
        }
    }
    for (int r = tid; r < KKEEP; r += 512) {
        int tok = si[r] + 1;
        kept_out[b * KKEEP + r] = (float)tok;
        kvmask[b * N_ + tok] = 1.0f;
    }
    if (tid == 0) kvmask[b * N_] = 1.0f;  // CLS always kept
}

// ---------------------------------------------------------------------------
// score_delta[h,n] = (1/B) * count_b(token n kept)   (n=0 -> 0)
// ---------------------------------------------------------------------------
__global__ void score_delta_kernel(const float* __restrict__ kvmask,
                                   float* __restrict__ sd) {
    int idx = blockIdx.x * 256 + threadIdx.x;
    if (idx >= H_ * N_) return;
    int n = idx % N_;
    float d = 0.f;
    if (n != 0) {
#pragma unroll
        for (int b = 0; b < B_; b++) d += kvmask[b * N_ + n];
    }
    sd[idx] = d * (1.0f / (float)B_);
}

// ---------------------------------------------------------------------------
// Pass CTX: masked renormalized context -> bf16 [b,n, h*64+d]
// ---------------------------------------------------------------------------
__global__ __launch_bounds__(256) void attn_ctx_mfma(const unsigned* __restrict__ qpk,
                                                     const unsigned* __restrict__ kpk,
                                                     const ushort* __restrict__ vt,
                                                     const float* __restrict__ w,
                                                     const float* __restrict__ kvmask,
                                                     ushort* __restrict__ ctxb) {
    __shared__ ushort Qh[4096], Ql[4096], Kh[4096], Kl[4096], Vt[4096], Pl[4096];
    __shared__ float wsld[64], mqs[64], mjs[64], red[4][64], inv[64];
    int bh = blockIdx.y, b = bh / H_, h = bh % H_;
    int q0 = blockIdx.x * 64;
    int tid = threadIdx.x, lane = tid & 63, wv = tid >> 6;
    int lr = lane & 15, ls = lane >> 4;
    const unsigned* qbase = qpk + (size_t)bh * N_ * D_;
    const unsigned* kbase = kpk + (size_t)bh * N_ * D_;
    const ushort* vtb = vt + (size_t)bh * 64 * VTS;
    stage_packed64(qbase, q0, Qh, Ql, tid);
    if (tid < 64) {
        int qn = q0 + tid;
        wsld[tid] = (qn < N_) ? w[(size_t)bh * N_ + qn] : 0.f;
        mqs[tid]  = (qn < N_) ? kvmask[b * N_ + qn] : 0.f;
    }
    __syncthreads();
    bf16x8_t fqh[4][2], fql[4][2];
#pragma unroll
    for (int i = 0; i < 4; i++)
#pragma unroll
        for (int c = 0; c < 2; c++) {
            fqh[i][c] = fragT(Qh, i * 16 + lr, c, ls);
            fql[i][c] = fragT(Ql, i * 16 + lr, c, ls);
        }
    float wq[4], mq[4];
#pragma unroll
    for (int i = 0; i < 4; i++) { wq[i] = wsld[i * 16 + lr]; mq[i] = mqs[i * 16 + lr]; }
    f32x4_t acc[4] = {};
    float psums[4] = {0.f, 0.f, 0.f, 0.f};
    for (int j0t = 0; j0t < N_; j0t += 64) {
        __syncthreads();
        stage_packed64(kbase, j0t, Kh, Kl, tid);
        stage_vt(vtb, j0t, Vt, tid);
        if (tid < 64) {
            int jn = j0t + tid;
            mjs[tid] = (jn < N_) ? kvmask[b * N_ + jn] : 0.f;
        }
        __syncthreads();
        bf16x8_t fkh[2], fkl[2];
#pragma unroll
        for (int c = 0; c < 2; c++) {
            fkh[c] = fragT(Kh, wv * 16 + lr, c, ls);
            fkl[c] = fragT(Kl, wv * 16 + lr, c, ls);
        }
        int jloc = wv * 16 + ls * 4;
#pragma unroll
        for (int i = 0; i < 4; i++) {
            f32x4_t s = {0.f, 0.f, 0.f, 0.f};
#pragma unroll
            for (int c = 0; c < 2; c++) {
                s = mfma_bf16(fkh[c], fqh[i][c], s);
                s = mfma_bf16(fkh[c], fql[i][c], s);
                s = mfma_bf16(fkl[c], fqh[i][c], s);
            }
            unsigned int pk[4];
            float wqi = wq[i], mqi = mq[i];
#pragma unroll
            for (int r = 0; r < 4; r++) {
                int j = j0t + jloc + r;
                float mj = mjs[jloc + r];
                float p = (j < N_) ? __expf(s[r]) * wqi : 0.f;
                p = (mqi > 0.5f || mj > 0.5f) ? p : 0.f;
                psums[i] += p;
                pk[r] = bf16rne(p);
            }
            int row = i * 16 + lr;
            int slot = ((wv << 1) + (ls >> 1)) ^ (row & 7);
            *(uint2*)&Pl[(row << 6) + (slot << 3) + ((ls & 1) << 2)] =
                make_uint2(pk[0] | (pk[1] << 16), pk[2] | (pk[3] << 16));
        }
        __syncthreads();
        bf16x8_t fv[2];
#pragma unroll
        for (int c = 0; c < 2; c++) fv[c] = fragT(Vt, wv * 16 + lr, c, ls);
#pragma unroll
        for (int i = 0; i < 4; i++) {
            bf16x8_t fp0 = fragT(Pl, i * 16 + lr, 0, ls);
            bf16x8_t fp1 = fragT(Pl, i * 16 + lr, 1, ls);
            acc[i] = mfma_bf16(fv[0], fp0, acc[i]);
            acc[i] = mfma_bf16(fv[1], fp1, acc[i]);
        }
    }
#pragma unroll
    for (int i = 0; i < 4; i++) {
        float v2 = psums[i];
        v2 += __shfl_xor(v2, 16);
        v2 += __shfl_xor(v2, 32);
        if (ls == 0) red[wv][i * 16 + lr] = v2;
    }
    __syncthreads();
    if (tid < 64) {
        float t = red[0][tid] + red[1][tid] + red[2][tid] + red[3][tid];
        inv[tid] = 1.0f / (t + 1e-8f);
    }
    __syncthreads();
#pragma unroll
    for (int i = 0; i < 4; i++) {
        int qn = q0 + i * 16 + lr;
        if (qn < N_) {
            float rn = inv[i * 16 + lr];
            unsigned int h0 = bf16rne(acc[i][0] * rn);
            unsigned int h1 = bf16rne(acc[i][1] * rn);
            unsigned int h2 = bf16rne(acc[i][2] * rn);
            unsigned int h3 = bf16rne(acc[i][3] * rn);
            *(uint2*)&ctxb[((size_t)(b * N_ + qn)) * C_ + h * D_ + wv * 16 + ls * 4] =
                make_uint2(h0 | (h1 << 16), h2 | (h3 << 16));
        }
    }
}

// ---------------------------------------------------------------------------
// MFMA GEMM 2 (plain bf16, prepacked W): out = context_bf16 @ Wproj^T + bproj
// ---------------------------------------------------------------------------
__global__ __launch_bounds__(256) void gemm_proj_mfma(const ushort* __restrict__ Actx,
                                                      const ushort* __restrict__ Wb,
                                                      const float* __restrict__ bias,
                                                      float* __restrict__ out) {
    __shared__ ushort Ab[128 * 32], Bb[128 * 32];
    const int tid = threadIdx.x;
    const int lane = tid & 63, wave = tid >> 6;
    const int wr = wave >> 1, wc = wave & 1;
    const int lr = lane & 15, ls = lane >> 4;
    const int m0 = blockIdx.y * 128, n0 = blockIdx.x * 128;
    const int srow = tid >> 1, shalf = tid & 1;
    const int arow = min(m0 + srow, M_TOT - 1);
    const ushort* aptr = Actx + (size_t)arow * C_ + shalf * 16;
    const ushort* bptr = Wb + (size_t)(n0 + srow) * C_ + shalf * 16;
    const int swz = (srow >> 1) & 3;
    const int sidx = srow * 32;
    const int p0 = (shalf * 2 + 0) ^ swz, p1 = (shalf * 2 + 1) ^ swz;
    f32x4_t acc[4][4] = {};
#pragma unroll 1
    for (int k0 = 0; k0 < C_; k0 += 32) {
        __syncthreads();
        {
            u32x4_t c0 = *(const u32x4_t*)(aptr + k0);
            u32x4_t c1 = *(const u32x4_t*)(aptr + k0 + 8);
            *(u32x4_t*)&Ab[sidx + p0 * 8] = c0;
            *(u32x4_t*)&Ab[sidx + p1 * 8] = c1;
        }
        {
            u32x4_t c0 = *(const u32x4_t*)(bptr + k0);
            u32x4_t c1 = *(const u32x4_t*)(bptr + k0 + 8);
            *(u32x4_t*)&Bb[sidx + p0 * 8] = c0;
            *(u32x4_t*)&Bb[sidx + p1 * 8] = c1;
        }
        __syncthreads();
        bf16x8_t fa[4], fb[4];
#pragma unroll
        for (int i = 0; i < 4; i++) {
            int rowA = wr * 64 + i * 16 + lr;
            int pa = ls ^ ((rowA >> 1) & 3);
            fa[i] = __builtin_bit_cast(bf16x8_t, *(const u32x4_t*)&Ab[rowA * 32 + pa * 8]);
            int rowB = wc * 64 + i * 16 + lr;
            int pb = ls ^ ((rowB >> 1) & 3);
            fb[i] = __builtin_bit_cast(bf16x8_t, *(const u32x4_t*)&Bb[rowB * 32 + pb * 8]);
        }
#pragma unroll
        for (int i = 0; i < 4; i++)
#pragma unroll
            for (int j = 0; j < 4; j++)
                acc[i][j] = mfma_bf16(fa[i], fb[j], acc[i][j]);
    }
#pragma unroll
    for (int j = 0; j < 4; j++) {
        int ng = n0 + wc * 64 + j * 16 + lr;
        float bb = bias[ng];
#pragma unroll
        for (int i = 0; i < 4; i++) {
            int mg0 = m0 + wr * 64 + i * 16 + ls * 4;
#pragma unroll
            for (int r = 0; r < 4; r++) {
                int m = mg0 + r;
                if (m < M_TOT) out[(size_t)m * C_ + ng] = acc[i][j][r] + bb;
            }
        }
    }
}

// ---------------------------------------------------------------------------
extern "C" void kernel_launch(void* const* d_in, const int* in_sizes, int n_in,
                              void* d_out, int out_size, void* d_ws, size_t ws_size,
                              hipStream_t stream) {
    const float* x     = (const float*)d_in[0];
    const float* ucb   = (const float*)d_in[1];
    const float* Wqkv  = (const float*)d_in[2];
    const float* Wproj = (const float*)d_in[3];
    const float* bproj = (const float*)d_in[4];
    const int*   counter = (const int*)d_in[5];

    const size_t SZ   = (size_t)B_ * H_ * N_ * D_;  // 7,090,176 (== M_TOT*C_)
    const size_t BHN  = (size_t)B_ * H_ * N_;       // 110,784
    const size_t XPL  = (size_t)(73 * 128) * C_;    // 7,176,192 (padded M x K)
    const size_t WPL  = (size_t)3 * C_ * C_;        // 1,769,472
    const size_t WPJ  = (size_t)C_ * C_;            // 589,824
    const size_t VTSZ = (size_t)B_ * H_ * D_ * VTS; // 7,864,320

    unsigned* qpk  = (unsigned*)d_ws;
    unsigned* kpk  = qpk + SZ;
    ushort*   XplH = (ushort*)(kpk + SZ);
    ushort*   XplL = XplH + XPL;
    ushort*   ctxb = XplH;                 // alias: planes dead after gemm_qkv
    ushort*   WplH = XplL + XPL;
    ushort*   WplL = WplH + WPL;
    ushort*   Wpjb = WplL + WPL;
    ushort*   vt   = Wpjb + WPJ;
    float*    w    = (float*)(vt + VTSZ);
    float*    colsum = w + BHN;
    float*    kvmask = colsum + BHN;
    size_t need = ((char*)(kvmask + (size_t)B_ * N_)) - (char*)d_ws;
    if (ws_size < need) {
        fprintf(stderr, "kernel_launch: ws too small, need %zu have %zu\n",
                need, ws_size);
        return;
    }

    float* out  = (float*)d_out;
    float* sd   = out + (size_t)B_ * N_ * C_;
    float* kept = sd + (size_t)H_ * N_;

    hipMemsetAsync(kvmask, 0, (size_t)B_ * N_ * sizeof(float), stream);
    hipMemsetAsync(vt, 0, VTSZ * sizeof(ushort), stream);

    pack_tiles_kernel<<<73 * NKT, 256, 0, stream>>>(x, XplH, XplL, M_TOT);
    pack_tiles_kernel<<<18 * NKT, 256, 0, stream>>>(Wqkv, WplH, WplL, 3 * C_);
    pack_rne_kernel<<<(int)(WPJ / 8 / 256), 256, 0, stream>>>(Wproj, Wpjb, (int)(WPJ / 8));

    gemm_qk_mfma<<<dim3(12, 73), 256, 0, stream>>>(XplH, XplL, WplH, WplL, qpk, kpk);
    gemm_v_mfma<<<dim3(6, 73), 256, 0, stream>>>(XplH, XplL, WplH, vt);
    attn_rowsum_mfma<<<dim3(10, B_ * H_), 256, 0, stream>>>(qpk, kpk, w);
    attn_colsum_mfma<<<dim3(10, B_ * H_), 256, 0, stream>>>(qpk, kpk, w, colsum);
    topk_kernel<<<B_, 512, 0, stream>>>(colsum, ucb, counter, kept, kvmask);
    score_delta_kernel<<<(H_ * N_ + 255) / 256, 256, 0, stream>>>(kvmask, sd);
    attn_ctx_mfma<<<dim3(10, B_ * H_), 256, 0, stream>>>(qpk, kpk, vt, w, kvmask, ctxb);
    gemm_proj_mfma<<<dim3(6, 73), 256, 0, stream>>>(ctxb, Wpjb, bproj, out);
}